// Round 3
// baseline (361.794 us; speedup 1.0000x reference)
//
#include <hip/hip_runtime.h>
#include <math.h>

// WaveletKANClassifier, MI355X gfx950. fp32 I/O, bf16 MFMA compute.
//
// Round-6: occupancy, not weight-load latency, is the wall. Evidence:
// round-1 (direct B loads) == round-2 (global_load_lds + counted vmcnt)
// == ~150 us; MfmaUtil 13.4% exactly matches the arithmetic for 2
// waves/SIMD (200 VGPR: acc[2][3]+wacc = 112 + ~88 arch); occupancy
// pinned ~22% in all rounds. With 2 waves/SIMD nothing hides latency.
// This round: block = 32 rows x 768 cols (was 64), 8 waves of 32x96,
// acc[3] = 48 regs, __launch_bounds__(512,4) -> target <=128 VGPR,
// 16 waves/CU (2 blocks/CU), grid 1024. Simple direct B-fragment
// global loads (compiler-scheduled); plain __syncthreads.

#define B_SZ  32768
#define DIN   768
#define DOUT  768
#define NWAV  48

// d_ws fragment-major layout (units: shorts). Fragment tile = 64 lanes x 8
// bf16 = 512 shorts; lane L holds M[c0+(L&31)][k0 + (L>>5)*8 + j].
#define WF_OFF   0        // W:  24 cb x 48 kb tiles = 589824
#define WPH_OFF  589824   // Wp hi: 2 ct x 48 kb = 49152
#define WPL_OFF  638976   // Wp lo: 49152
#define WCF_OFF  688128   // Wc: 24 cb x 3 kb = 36864
#define WL_OFF   724992   // worklist: u32 count + u32 rows[WL_CAP-1]
#define WL_CAP   8192

typedef short bf16x4 __attribute__((ext_vector_type(4)));
typedef short bf16x8 __attribute__((ext_vector_type(8)));
typedef float f32x16 __attribute__((ext_vector_type(16)));

__device__ __forceinline__ float bf2f(short u) {
    union { unsigned int i; float f; } v;
    v.i = ((unsigned int)(unsigned short)u) << 16;
    return v.f;
}
__device__ __forceinline__ short f2bf(float f) {
    union { float f; unsigned int i; } v; v.f = f;
    unsigned int r = v.i + 0x7FFFu + ((v.i >> 16) & 1u);  // RNE
    return (short)(r >> 16);
}

// ---------------------------------------------------------------- K0: pack
__global__ __launch_bounds__(256) void pack_kernel(
    const float* __restrict__ W, const float* __restrict__ Wp,
    const float* __restrict__ Wc, short* __restrict__ ws)
{
    if (blockIdx.x == 0 && threadIdx.x == 0)
        *reinterpret_cast<unsigned*>(ws + WL_OFF) = 0u;  // reset worklist

    const int gw = (blockIdx.x * 256 + threadIdx.x) >> 6;
    const int L  = threadIdx.x & 63;
    const int lm = L & 31, half = L >> 5;

    if (gw < 1152) {                       // W [768 x 768]
        const int cb = gw / 48, kb = gw % 48;
        const int row = cb * 32 + lm;
        const int k = kb * 16 + half * 8;
        bf16x8 o;
#pragma unroll
        for (int j = 0; j < 8; j++) o[j] = f2bf(W[(size_t)row * DIN + k + j]);
        *reinterpret_cast<bf16x8*>(&ws[WF_OFF + (size_t)gw * 512 + L * 8]) = o;
    } else if (gw < 1248) {                // Wp [48 x 768], hi/lo, pad rows->64
        const int t = gw - 1152;
        const int ct = t / 48, kb = t % 48;
        const int j = ct * 32 + lm;
        const int k = kb * 16 + half * 8;
        bf16x8 h, l;
#pragma unroll
        for (int jj = 0; jj < 8; jj++) {
            float v = (j < NWAV) ? Wp[(size_t)j * DIN + k + jj] : 0.f;
            const short hh = f2bf(v);
            h[jj] = hh;
            l[jj] = f2bf(v - bf2f(hh));
        }
        *reinterpret_cast<bf16x8*>(&ws[WPH_OFF + (size_t)t * 512 + L * 8]) = h;
        *reinterpret_cast<bf16x8*>(&ws[WPL_OFF + (size_t)t * 512 + L * 8]) = l;
    } else if (gw < 1320) {                // Wc [768 x 48]
        const int t = gw - 1248;
        const int cb = t / 3, kb = t % 3;
        const int row = cb * 32 + lm;
        const int k = kb * 16 + half * 8;
        bf16x8 o;
#pragma unroll
        for (int jj = 0; jj < 8; jj++) o[jj] = f2bf(Wc[(size_t)row * NWAV + k + jj]);
        *reinterpret_cast<bf16x8*>(&ws[WCF_OFF + (size_t)t * 512 + L * 8]) = o;
    }
}

// ---------------------------------------------------------------- K1: fused
// 32 rows x 768 cols per block, 8 waves x [32r x 96c], 1024 blocks.
__global__ __launch_bounds__(512, 4) void fused_kernel(
    const float* __restrict__ x, const short* __restrict__ ws,
    unsigned* __restrict__ wl,
    const float* __restrict__ bp, const float* __restrict__ sc,
    const float* __restrict__ tr,
    const float* __restrict__ bb, const float* __restrict__ bc,
    const float* __restrict__ gm, const float* __restrict__ bt,
    float* __restrict__ out)
{
    // x tiles: 32 rows x 64 k bf16, row stride 72 shorts (9x16B granules,
    // coprime 8 -> near-conflict-free b128 frag reads). Double-buffered.
    __shared__ __align__(16) short xh[2][32 * 72];
    __shared__ __align__(16) short xl[2][32 * 72];
    __shared__ float redS[32 * 8], redQ[32 * 8];
    __shared__ float muA[32], rsA[32];

    const short* WF  = ws + WF_OFF;
    const short* WPH = ws + WPH_OFF;
    const short* WPL = ws + WPL_OFF;
    const short* WCF = ws + WCF_OFF;

    const int tid = threadIdx.x;
    const int r0  = blockIdx.x * 32;
    const int L   = tid & 63;
    const int wv  = __builtin_amdgcn_readfirstlane(tid >> 6);  // wave-uniform
    const int lm  = L & 31, half = L >> 5;
    const int L8  = L * 8;
    const bool wi = (wv < 2);      // waves 0,1 also compute wi = x@Wp^T
    const int wv3 = wv * 3;

    f32x16 acc[3];                 // [ct]: cols wv*96 + ct*32, rows 0..32
#pragma unroll
    for (int ct = 0; ct < 3; ct++)
#pragma unroll
        for (int g = 0; g < 16; g++) acc[ct][g] = 0.f;
    f32x16 wacc;                   // wi acc (waves 0,1)
#pragma unroll
    for (int g = 0; g < 16; g++) wacc[g] = 0.f;

    // staging role: thread -> (row, 4-k chunk); 16 threads per row
    const int srow = tid >> 4;
    const int sk   = (tid & 15) * 4;

    // ---- prologue: stage x chunk 0 into buf 0
    {
        const float4 v = *reinterpret_cast<const float4*>(
            &x[(size_t)(r0 + srow) * DIN + sk]);
        bf16x4 hh, ll;
        const float f[4] = {v.x, v.y, v.z, v.w};
#pragma unroll
        for (int i = 0; i < 4; i++) {
            const short h = f2bf(f[i]);
            hh[i] = h;
            ll[i] = f2bf(f[i] - bf2f(h));
        }
        *reinterpret_cast<bf16x4*>(&xh[0][srow * 72 + sk]) = hh;
        *reinterpret_cast<bf16x4*>(&xl[0][srow * 72 + sk]) = ll;
    }
    __syncthreads();

    // ---- K loop: 12 chunks of 64
    for (int k0i = 0; k0i < 12; ++k0i) {
        const int cur = k0i & 1;
        float4 v;
        if (k0i < 11) {  // prefetch next x chunk (hidden under compute)
            v = *reinterpret_cast<const float4*>(
                &x[(size_t)(r0 + srow) * DIN + (k0i + 1) * 64 + sk]);
        }
        const int kb0 = k0i * 4;

#pragma unroll
        for (int ks = 0; ks < 4; ++ks) {
            const bf16x8 a0 = *reinterpret_cast<bf16x8*>(
                &xh[cur][lm * 72 + ks * 16 + half * 8]);
#pragma unroll
            for (int ct = 0; ct < 3; ++ct) {
                const bf16x8 b = *reinterpret_cast<const bf16x8*>(
                    &WF[((size_t)((wv3 + ct) * 48 + kb0 + ks)) * 512 + L8]);
                acc[ct] = __builtin_amdgcn_mfma_f32_32x32x16_bf16(a0, b, acc[ct], 0, 0, 0);
            }
            if (wi) {   // split-bf16 wi path: 3 MFMA
                const bf16x8 al = *reinterpret_cast<bf16x8*>(
                    &xl[cur][lm * 72 + ks * 16 + half * 8]);
                const bf16x8 bh = *reinterpret_cast<const bf16x8*>(
                    &WPH[((size_t)(wv * 48 + kb0 + ks)) * 512 + L8]);
                const bf16x8 bl = *reinterpret_cast<const bf16x8*>(
                    &WPL[((size_t)(wv * 48 + kb0 + ks)) * 512 + L8]);
                wacc = __builtin_amdgcn_mfma_f32_32x32x16_bf16(a0, bl, wacc, 0, 0, 0);
                wacc = __builtin_amdgcn_mfma_f32_32x32x16_bf16(al, bh, wacc, 0, 0, 0);
                wacc = __builtin_amdgcn_mfma_f32_32x32x16_bf16(a0, bh, wacc, 0, 0, 0);
            }
        }

        // stage next x chunk into 1-cur
        if (k0i < 11) {
            bf16x4 hh, ll;
            const float f[4] = {v.x, v.y, v.z, v.w};
#pragma unroll
            for (int i = 0; i < 4; i++) {
                const short h = f2bf(f[i]);
                hh[i] = h;
                ll[i] = f2bf(f[i] - bf2f(h));
            }
            *reinterpret_cast<bf16x4*>(&xh[1 - cur][srow * 72 + sk]) = hh;
            *reinterpret_cast<bf16x4*>(&xl[1 - cur][srow * 72 + sk]) = ll;
        }
        __syncthreads();
    }

    // ---- wavelet activation + GELU -> wav tile in LDS (reuse xh[0])
    short* wavL = &xh[0][0];
    if (wi) {
        const int j = wv * 32 + lm;
        if (j < NWAV) {
            const float bpv = bp[j], scv = sc[j], trv = tr[j];
#pragma unroll
            for (int g = 0; g < 16; ++g) {
                const int rowl = (g & 3) + 8 * (g >> 2) + 4 * half;   // C/D map
                const float wiv = wacc[g] + bpv;
                const float s = (wiv - trv) / scv;
                float w;
                if (j < 16) {
                    // haar: flag boundary band rows for fix_kernel
                    const float dmin = fminf(fabsf(s), fminf(fabsf(s - 0.5f), fabsf(s - 1.0f)));
                    if (dmin < 2e-4f) {
                        const unsigned idx = atomicAdd(&wl[0], 1u);
                        if (idx < WL_CAP - 1) wl[1 + idx] = (unsigned)(r0 + rowl);
                    }
                    w = (s >= 0.f && s < 0.5f) ? 1.f : ((s >= 0.5f && s < 1.f) ? -1.f : 0.f);
                } else if (j < 32) {
                    w = (1.f - s * s) * expf(-0.5f * s * s);
                } else {
                    w = cosf(5.f * s) * expf(-0.5f * s * s);
                }
                const float gel = 0.5f * w * (1.f + erff(w * 0.70710678118654752f));
                wavL[rowl * 72 + j] = f2bf(gel);
            }
        }
    }
    __syncthreads();

    // ---- h += wav @ Wc^T  (K=48 -> 3 ksteps)
#pragma unroll
    for (int ks = 0; ks < 3; ++ks) {
        const bf16x8 a0 = *reinterpret_cast<bf16x8*>(
            &wavL[lm * 72 + ks * 16 + half * 8]);
#pragma unroll
        for (int ct = 0; ct < 3; ++ct) {
            const bf16x8 b = *reinterpret_cast<const bf16x8*>(
                &WCF[((size_t)((wv3 + ct) * 3 + ks)) * 512 + L8]);
            acc[ct] = __builtin_amdgcn_mfma_f32_32x32x16_bf16(a0, b, acc[ct], 0, 0, 0);
        }
    }

    // ---- bias + LN reduction
    float bias[3], gmv[3], btv[3];
#pragma unroll
    for (int ct = 0; ct < 3; ++ct) {
        const int col = wv * 96 + ct * 32 + lm;
        bias[ct] = bb[col] + bc[col];
        gmv[ct] = gm[col];
        btv[ct] = bt[col];
    }
#pragma unroll
    for (int g = 0; g < 16; ++g) {
        const float v0 = acc[0][g] + bias[0];
        const float v1 = acc[1][g] + bias[1];
        const float v2 = acc[2][g] + bias[2];
        acc[0][g] = v0; acc[1][g] = v1; acc[2][g] = v2;
        float s1 = v0 + v1 + v2;
        float s2 = v0 * v0 + v1 * v1 + v2 * v2;
        // reduce across the 32 lanes of this half (same output row)
        s1 += __shfl_xor(s1, 1);  s2 += __shfl_xor(s2, 1);
        s1 += __shfl_xor(s1, 2);  s2 += __shfl_xor(s2, 2);
        s1 += __shfl_xor(s1, 4);  s2 += __shfl_xor(s2, 4);
        s1 += __shfl_xor(s1, 8);  s2 += __shfl_xor(s2, 8);
        s1 += __shfl_xor(s1, 16); s2 += __shfl_xor(s2, 16);
        if (lm == 0) {
            const int rowl = (g & 3) + 8 * (g >> 2) + 4 * half;
            redS[rowl * 8 + wv] = s1;
            redQ[rowl * 8 + wv] = s2;
        }
    }
    __syncthreads();
    if (tid < 32) {
        float S = 0.f, Q = 0.f;
#pragma unroll
        for (int i = 0; i < 8; i++) { S += redS[tid * 8 + i]; Q += redQ[tid * 8 + i]; }
        const float mu = S * (1.f / 768.f);
        const float var = Q * (1.f / 768.f) - mu * mu;
        muA[tid] = mu;
        rsA[tid] = rsqrtf(var + 1e-5f);
    }
    __syncthreads();

    // ---- normalize + store (f32)
#pragma unroll
    for (int g = 0; g < 16; ++g) {
        const int rowl = (g & 3) + 8 * (g >> 2) + 4 * half;
        const float mu = muA[rowl], rs = rsA[rowl];
        float* orow = &out[(size_t)(r0 + rowl) * DOUT + wv * 96 + lm];
#pragma unroll
        for (int ct = 0; ct < 3; ++ct) {
            orow[ct * 32] = (acc[ct][g] - mu) * rs * gmv[ct] + btv[ct];
        }
    }
}

// ---------------------------------------------------------------- K2: fix
// Recompute flagged rows: fp64 wi + haar classify, fp32 everything else.
__global__ __launch_bounds__(256) void fix_kernel(
    const float* __restrict__ x, const float* __restrict__ W,
    const float* __restrict__ bb, const float* __restrict__ Wp,
    const float* __restrict__ bp, const float* __restrict__ Wc,
    const float* __restrict__ bc, const float* __restrict__ sc,
    const float* __restrict__ tr, const float* __restrict__ gm,
    const float* __restrict__ bt, const unsigned* __restrict__ wl,
    float* __restrict__ out)
{
    __shared__ float  xrow[DIN];
    __shared__ double wpart[NWAV][4];
    __shared__ float  wavS[NWAV];
    __shared__ float  hrow[DOUT];
    __shared__ float  redS2[4], redQ2[4];
    __shared__ float  mu_s, rs_s;

    unsigned cnt = wl[0];
    if (cnt > WL_CAP - 1) cnt = WL_CAP - 1;
    const int tid = threadIdx.x;

    for (unsigned it = blockIdx.x; it < cnt; it += gridDim.x) {
        const int row = (int)wl[1 + it];

        for (int k = tid; k < DIN; k += 256) xrow[k] = x[(size_t)row * DIN + k];
        __syncthreads();

        if (tid < NWAV * 4) {
            const int j = tid >> 2, q = tid & 3;
            const float* wr = &Wp[(size_t)j * DIN + q * 192];
            const float* xr = &xrow[q * 192];
            double a0 = 0.0, a1 = 0.0, a2 = 0.0, a3 = 0.0;
            for (int k = 0; k < 192; k += 4) {
                a0 = fma((double)xr[k + 0], (double)wr[k + 0], a0);
                a1 = fma((double)xr[k + 1], (double)wr[k + 1], a1);
                a2 = fma((double)xr[k + 2], (double)wr[k + 2], a2);
                a3 = fma((double)xr[k + 3], (double)wr[k + 3], a3);
            }
            wpart[j][q] = (a0 + a1) + (a2 + a3);
        }
        __syncthreads();
        if (tid < NWAV) {
            const int j = tid;
            const double wid = ((wpart[j][0] + wpart[j][1]) +
                                (wpart[j][2] + wpart[j][3])) + (double)bp[j];
            const double sd = (wid - (double)tr[j]) / (double)sc[j];
            double w;
            if (j < 16) {
                w = (sd >= 0.0 && sd < 0.5) ? 1.0 : ((sd >= 0.5 && sd < 1.0) ? -1.0 : 0.0);
            } else if (j < 32) {
                w = (1.0 - sd * sd) * exp(-0.5 * sd * sd);
            } else {
                w = cos(5.0 * sd) * exp(-0.5 * sd * sd);
            }
            const double gel = 0.5 * w * (1.0 + erf(w * 0.70710678118654752));
            wavS[j] = (float)gel;
        }
        __syncthreads();

        // h[row, c] for all c (3 cols/thread), fp32 direct accumulate
        for (int c = tid; c < DOUT; c += 256) {
            const float* wr = &W[(size_t)c * DIN];
            float a0 = 0.f, a1 = 0.f, a2 = 0.f, a3 = 0.f;
            for (int k = 0; k < DIN; k += 4) {
                a0 = fmaf(xrow[k + 0], wr[k + 0], a0);
                a1 = fmaf(xrow[k + 1], wr[k + 1], a1);
                a2 = fmaf(xrow[k + 2], wr[k + 2], a2);
                a3 = fmaf(xrow[k + 3], wr[k + 3], a3);
            }
            float wp_ = 0.f;
            const float* wcr = &Wc[(size_t)c * NWAV];
#pragma unroll
            for (int j = 0; j < NWAV; j++) wp_ += wavS[j] * wcr[j];
            hrow[c] = ((a0 + a1) + (a2 + a3)) + bb[c] + wp_ + bc[c];
        }
        __syncthreads();

        float S = 0.f, Q = 0.f;
        for (int c = tid; c < DOUT; c += 256) { const float v = hrow[c]; S += v; Q += v * v; }
        S += __shfl_xor(S, 1);  Q += __shfl_xor(Q, 1);
        S += __shfl_xor(S, 2);  Q += __shfl_xor(Q, 2);
        S += __shfl_xor(S, 4);  Q += __shfl_xor(Q, 4);
        S += __shfl_xor(S, 8);  Q += __shfl_xor(Q, 8);
        S += __shfl_xor(S, 16); Q += __shfl_xor(Q, 16);
        S += __shfl_xor(S, 32); Q += __shfl_xor(Q, 32);
        if ((tid & 63) == 0) { redS2[tid >> 6] = S; redQ2[tid >> 6] = Q; }
        __syncthreads();
        if (tid == 0) {
            float Ss = 0.f, Qs = 0.f;
#pragma unroll
            for (int i = 0; i < 4; i++) { Ss += redS2[i]; Qs += redQ2[i]; }
            const float mu = Ss * (1.f / 768.f);
            const float var = Qs * (1.f / 768.f) - mu * mu;
            mu_s = mu;
            rs_s = rsqrtf(var + 1e-5f);
        }
        __syncthreads();
        for (int c = tid; c < DOUT; c += 256)
            out[(size_t)row * DOUT + c] = (hrow[c] - mu_s) * rs_s * gm[c] + bt[c];
        __syncthreads();
    }
}

// ---------------------------------------------------------------- launcher
extern "C" void kernel_launch(void* const* d_in, const int* in_sizes, int n_in,
                              void* d_out, int out_size, void* d_ws, size_t ws_size,
                              hipStream_t stream)
{
    const float* x  = (const float*)d_in[0];
    const float* W  = (const float*)d_in[1];
    const float* b  = (const float*)d_in[2];
    const float* Wp = (const float*)d_in[3];
    const float* bp = (const float*)d_in[4];
    const float* Wc = (const float*)d_in[5];
    const float* bc = (const float*)d_in[6];
    const float* sc = (const float*)d_in[7];
    const float* tr = (const float*)d_in[8];
    const float* gm = (const float*)d_in[9];
    const float* bt = (const float*)d_in[10];
    float* out = (float*)d_out;
    short* ws  = (short*)d_ws;
    unsigned* wl = reinterpret_cast<unsigned*>(ws + WL_OFF);

    pack_kernel<<<dim3(330), dim3(256), 0, stream>>>(W, Wp, Wc, ws);
    fused_kernel<<<dim3(B_SZ / 32), dim3(512), 0, stream>>>(
        x, ws, wl, bp, sc, tr, b, bc, gm, bt, out);
    fix_kernel<<<dim3(256), dim3(256), 0, stream>>>(
        x, W, b, Wp, bp, Wc, bc, sc, tr, gm, bt, wl, out);
}

// Round 4
// 295.478 us; speedup vs baseline: 1.2244x; 1.2244x over previous
//
#include <hip/hip_runtime.h>
#include <math.h>

// WaveletKANClassifier, MI355X gfx950. fp32 I/O, bf16 MFMA compute.
//
// Round-7: dispatch-count is the live lever. Evidence: fused invariant at
// 148-154 us across {direct-load vs DMA, 2 vs 3.5 waves/SIMD, 64 vs 32-row
// tiles} (all per-CU resource totals constant -> unknown per-CU throughput
// pin); meanwhile total-minus-fused = 136 us at 2 dispatches (R0) vs ~208 us
// at 3 dispatches (R1-3), and fix_kernel's compute is ~10 us by arithmetic
// => ~63 us fixed overhead per dispatch in the timed loop.
// This round:
//  - fix_kernel ELIMINATED: haar boundary recheck is back inside fused, but
//    block-parallel (512-thread fp64 dot per flagged (row,j), LDS bitmask,
//    patches wavL before the Wc MFMA). ~1 us per trigger, ~250 triggers
//    chip-wide. 2 dispatches total.
//  - nontemporal x loads + out stores: the 200 MB stream stops evicting the
//    1.45 MB packed-weight image from L2 (tests weight-L2-thrash theory).

#define B_SZ  32768
#define DIN   768
#define DOUT  768
#define NWAV  48

// d_ws fragment-major layout (units: shorts). Fragment tile = 64 lanes x 8
// bf16 = 512 shorts; lane L holds M[c0+(L&31)][k0 + (L>>5)*8 + j].
#define WF_OFF   0        // W:  24 cb x 48 kb tiles = 589824
#define WPH_OFF  589824   // Wp hi: 2 ct x 48 kb = 49152
#define WPL_OFF  638976   // Wp lo: 49152
#define WCF_OFF  688128   // Wc: 24 cb x 3 kb = 36864

typedef short bf16x4 __attribute__((ext_vector_type(4)));
typedef short bf16x8 __attribute__((ext_vector_type(8)));
typedef float f32x4  __attribute__((ext_vector_type(4)));
typedef float f32x16 __attribute__((ext_vector_type(16)));

__device__ __forceinline__ float bf2f(short u) {
    union { unsigned int i; float f; } v;
    v.i = ((unsigned int)(unsigned short)u) << 16;
    return v.f;
}
__device__ __forceinline__ short f2bf(float f) {
    union { float f; unsigned int i; } v; v.f = f;
    unsigned int r = v.i + 0x7FFFu + ((v.i >> 16) & 1u);  // RNE
    return (short)(r >> 16);
}

// ---------------------------------------------------------------- K0: pack
__global__ __launch_bounds__(256) void pack_kernel(
    const float* __restrict__ W, const float* __restrict__ Wp,
    const float* __restrict__ Wc, short* __restrict__ ws)
{
    const int gw = (blockIdx.x * 256 + threadIdx.x) >> 6;
    const int L  = threadIdx.x & 63;
    const int lm = L & 31, half = L >> 5;

    if (gw < 1152) {                       // W [768 x 768]
        const int cb = gw / 48, kb = gw % 48;
        const int row = cb * 32 + lm;
        const int k = kb * 16 + half * 8;
        bf16x8 o;
#pragma unroll
        for (int j = 0; j < 8; j++)
            o[j] = f2bf(__builtin_nontemporal_load(&W[(size_t)row * DIN + k + j]));
        *reinterpret_cast<bf16x8*>(&ws[WF_OFF + (size_t)gw * 512 + L * 8]) = o;
    } else if (gw < 1248) {                // Wp [48 x 768], hi/lo, pad rows->64
        const int t = gw - 1152;
        const int ct = t / 48, kb = t % 48;
        const int j = ct * 32 + lm;
        const int k = kb * 16 + half * 8;
        bf16x8 h, l;
#pragma unroll
        for (int jj = 0; jj < 8; jj++) {
            float v = (j < NWAV) ? Wp[(size_t)j * DIN + k + jj] : 0.f;
            const short hh = f2bf(v);
            h[jj] = hh;
            l[jj] = f2bf(v - bf2f(hh));
        }
        *reinterpret_cast<bf16x8*>(&ws[WPH_OFF + (size_t)t * 512 + L * 8]) = h;
        *reinterpret_cast<bf16x8*>(&ws[WPL_OFF + (size_t)t * 512 + L * 8]) = l;
    } else if (gw < 1320) {                // Wc [768 x 48]
        const int t = gw - 1248;
        const int cb = t / 3, kb = t % 3;
        const int row = cb * 32 + lm;
        const int k = kb * 16 + half * 8;
        bf16x8 o;
#pragma unroll
        for (int jj = 0; jj < 8; jj++) o[jj] = f2bf(Wc[(size_t)row * NWAV + k + jj]);
        *reinterpret_cast<bf16x8*>(&ws[WCF_OFF + (size_t)t * 512 + L * 8]) = o;
    }
}

// ---------------------------------------------------------------- K1: fused
// 32 rows x 768 cols per block, 8 waves x [32r x 96c], 1024 blocks.
__global__ __launch_bounds__(512, 4) void fused_kernel(
    const float* __restrict__ x, const short* __restrict__ ws,
    const float* __restrict__ Wp,
    const float* __restrict__ bp, const float* __restrict__ sc,
    const float* __restrict__ tr,
    const float* __restrict__ bb, const float* __restrict__ bc,
    const float* __restrict__ gm, const float* __restrict__ bt,
    float* __restrict__ out)
{
    // x tiles: 32 rows x 64 k bf16, row stride 72 shorts (9x16B granules,
    // coprime 8 -> near-conflict-free b128 frag reads). Double-buffered.
    __shared__ __align__(16) short xh[2][32 * 72];
    __shared__ __align__(16) short xl[2][32 * 72];
    __shared__ float redS[32 * 8], redQ[32 * 8];
    __shared__ float muA[32], rsA[32];
    __shared__ unsigned flags[32];      // bit j: (row, haar j) boundary band
    __shared__ double dred[8];

    const short* WF  = ws + WF_OFF;
    const short* WPH = ws + WPH_OFF;
    const short* WPL = ws + WPL_OFF;
    const short* WCF = ws + WCF_OFF;

    const int tid = threadIdx.x;
    const int r0  = blockIdx.x * 32;
    const int L   = tid & 63;
    const int wv  = __builtin_amdgcn_readfirstlane(tid >> 6);  // wave-uniform
    const int lm  = L & 31, half = L >> 5;
    const int L8  = L * 8;
    const bool wi = (wv < 2);      // waves 0,1 also compute wi = x@Wp^T
    const int wv3 = wv * 3;

    if (tid < 32) flags[tid] = 0u;

    f32x16 acc[3];                 // [ct]: cols wv*96 + ct*32, rows 0..32
#pragma unroll
    for (int ct = 0; ct < 3; ct++)
#pragma unroll
        for (int g = 0; g < 16; g++) acc[ct][g] = 0.f;
    f32x16 wacc;                   // wi acc (waves 0,1)
#pragma unroll
    for (int g = 0; g < 16; g++) wacc[g] = 0.f;

    // staging role: thread -> (row, 4-k chunk); 16 threads per row
    const int srow = tid >> 4;
    const int sk   = (tid & 15) * 4;

    // ---- prologue: stage x chunk 0 into buf 0
    {
        const f32x4 v = __builtin_nontemporal_load(
            reinterpret_cast<const f32x4*>(&x[(size_t)(r0 + srow) * DIN + sk]));
        bf16x4 hh, ll;
#pragma unroll
        for (int i = 0; i < 4; i++) {
            const short h = f2bf(v[i]);
            hh[i] = h;
            ll[i] = f2bf(v[i] - bf2f(h));
        }
        *reinterpret_cast<bf16x4*>(&xh[0][srow * 72 + sk]) = hh;
        *reinterpret_cast<bf16x4*>(&xl[0][srow * 72 + sk]) = ll;
    }
    __syncthreads();

    // ---- K loop: 12 chunks of 64
    for (int k0i = 0; k0i < 12; ++k0i) {
        const int cur = k0i & 1;
        f32x4 v;
        if (k0i < 11) {  // prefetch next x chunk (hidden under compute)
            v = __builtin_nontemporal_load(reinterpret_cast<const f32x4*>(
                &x[(size_t)(r0 + srow) * DIN + (k0i + 1) * 64 + sk]));
        }
        const int kb0 = k0i * 4;

#pragma unroll
        for (int ks = 0; ks < 4; ++ks) {
            const bf16x8 a0 = *reinterpret_cast<bf16x8*>(
                &xh[cur][lm * 72 + ks * 16 + half * 8]);
#pragma unroll
            for (int ct = 0; ct < 3; ++ct) {
                const bf16x8 b = *reinterpret_cast<const bf16x8*>(
                    &WF[((size_t)((wv3 + ct) * 48 + kb0 + ks)) * 512 + L8]);
                acc[ct] = __builtin_amdgcn_mfma_f32_32x32x16_bf16(a0, b, acc[ct], 0, 0, 0);
            }
            if (wi) {   // split-bf16 wi path: 3 MFMA
                const bf16x8 al = *reinterpret_cast<bf16x8*>(
                    &xl[cur][lm * 72 + ks * 16 + half * 8]);
                const bf16x8 bh = *reinterpret_cast<const bf16x8*>(
                    &WPH[((size_t)(wv * 48 + kb0 + ks)) * 512 + L8]);
                const bf16x8 bl = *reinterpret_cast<const bf16x8*>(
                    &WPL[((size_t)(wv * 48 + kb0 + ks)) * 512 + L8]);
                wacc = __builtin_amdgcn_mfma_f32_32x32x16_bf16(a0, bl, wacc, 0, 0, 0);
                wacc = __builtin_amdgcn_mfma_f32_32x32x16_bf16(al, bh, wacc, 0, 0, 0);
                wacc = __builtin_amdgcn_mfma_f32_32x32x16_bf16(a0, bh, wacc, 0, 0, 0);
            }
        }

        // stage next x chunk into 1-cur
        if (k0i < 11) {
            bf16x4 hh, ll;
#pragma unroll
            for (int i = 0; i < 4; i++) {
                const short h = f2bf(v[i]);
                hh[i] = h;
                ll[i] = f2bf(v[i] - bf2f(h));
            }
            *reinterpret_cast<bf16x4*>(&xh[1 - cur][srow * 72 + sk]) = hh;
            *reinterpret_cast<bf16x4*>(&xl[1 - cur][srow * 72 + sk]) = ll;
        }
        __syncthreads();
    }

    // ---- wavelet activation + GELU -> wav tile in LDS (reuse xh[0])
    short* wavL = &xh[0][0];
    if (wi) {
        const int j = wv * 32 + lm;
        if (j < NWAV) {
            const float bpv = bp[j], scv = sc[j], trv = tr[j];
#pragma unroll
            for (int g = 0; g < 16; ++g) {
                const int rowl = (g & 3) + 8 * (g >> 2) + 4 * half;   // C/D map
                const float wiv = wacc[g] + bpv;
                const float s = (wiv - trv) / scv;
                float w;
                if (j < 16) {
                    // haar: flag boundary band for the in-block fp64 recheck
                    const float dmin = fminf(fabsf(s), fminf(fabsf(s - 0.5f), fabsf(s - 1.0f)));
                    if (dmin < 2e-4f) atomicOr(&flags[rowl], 1u << j);
                    w = (s >= 0.f && s < 0.5f) ? 1.f : ((s >= 0.5f && s < 1.f) ? -1.f : 0.f);
                } else if (j < 32) {
                    w = (1.f - s * s) * expf(-0.5f * s * s);
                } else {
                    w = cosf(5.f * s) * expf(-0.5f * s * s);
                }
                const float gel = 0.5f * w * (1.f + erff(w * 0.70710678118654752f));
                wavL[rowl * 72 + j] = f2bf(gel);
            }
        }
    }
    __syncthreads();

    // ---- block-parallel fp64 recheck of flagged (row, j) haar entries.
    // Rare (~25% of blocks have >=1 flag). Uniform control flow: all 512
    // threads walk the same LDS flag words; each recheck is a cooperative
    // 768-term fp64 dot (~1 us), patching wavL before the Wc MFMA.
#pragma unroll 1
    for (int fr = 0; fr < 32; ++fr) {
        unsigned m = flags[fr];
        while (m) {
            const int j = __ffs(m) - 1;
            m &= m - 1;
            const float* xr = &x[(size_t)(r0 + fr) * DIN];
            const float* wr = &Wp[(size_t)j * DIN];
            double a = (double)xr[tid] * (double)wr[tid];
            if (tid < DIN - 512)
                a += (double)xr[tid + 512] * (double)wr[tid + 512];
            a += __shfl_xor(a, 1);  a += __shfl_xor(a, 2);
            a += __shfl_xor(a, 4);  a += __shfl_xor(a, 8);
            a += __shfl_xor(a, 16); a += __shfl_xor(a, 32);
            if (L == 0) dred[wv] = a;
            __syncthreads();
            if (tid == 0) {
                double wid = (double)bp[j];
#pragma unroll
                for (int i = 0; i < 8; i++) wid += dred[i];
                const double sd = (wid - (double)tr[j]) / (double)sc[j];
                const double w = (sd >= 0.0 && sd < 0.5) ? 1.0
                               : ((sd >= 0.5 && sd < 1.0) ? -1.0 : 0.0);
                const double gel = 0.5 * w * (1.0 + erf(w * 0.70710678118654752));
                wavL[fr * 72 + j] = f2bf((float)gel);
            }
            __syncthreads();
        }
    }

    // ---- h += wav @ Wc^T  (K=48 -> 3 ksteps)
#pragma unroll
    for (int ks = 0; ks < 3; ++ks) {
        const bf16x8 a0 = *reinterpret_cast<bf16x8*>(
            &wavL[lm * 72 + ks * 16 + half * 8]);
#pragma unroll
        for (int ct = 0; ct < 3; ++ct) {
            const bf16x8 b = *reinterpret_cast<const bf16x8*>(
                &WCF[((size_t)((wv3 + ct) * 3 + ks)) * 512 + L8]);
            acc[ct] = __builtin_amdgcn_mfma_f32_32x32x16_bf16(a0, b, acc[ct], 0, 0, 0);
        }
    }

    // ---- bias + LN reduction
    float bias[3], gmv[3], btv[3];
#pragma unroll
    for (int ct = 0; ct < 3; ++ct) {
        const int col = wv * 96 + ct * 32 + lm;
        bias[ct] = bb[col] + bc[col];
        gmv[ct] = gm[col];
        btv[ct] = bt[col];
    }
#pragma unroll
    for (int g = 0; g < 16; ++g) {
        const float v0 = acc[0][g] + bias[0];
        const float v1 = acc[1][g] + bias[1];
        const float v2 = acc[2][g] + bias[2];
        acc[0][g] = v0; acc[1][g] = v1; acc[2][g] = v2;
        float s1 = v0 + v1 + v2;
        float s2 = v0 * v0 + v1 * v1 + v2 * v2;
        // reduce across the 32 lanes of this half (same output row)
        s1 += __shfl_xor(s1, 1);  s2 += __shfl_xor(s2, 1);
        s1 += __shfl_xor(s1, 2);  s2 += __shfl_xor(s2, 2);
        s1 += __shfl_xor(s1, 4);  s2 += __shfl_xor(s2, 4);
        s1 += __shfl_xor(s1, 8);  s2 += __shfl_xor(s2, 8);
        s1 += __shfl_xor(s1, 16); s2 += __shfl_xor(s2, 16);
        if (lm == 0) {
            const int rowl = (g & 3) + 8 * (g >> 2) + 4 * half;
            redS[rowl * 8 + wv] = s1;
            redQ[rowl * 8 + wv] = s2;
        }
    }
    __syncthreads();
    if (tid < 32) {
        float S = 0.f, Q = 0.f;
#pragma unroll
        for (int i = 0; i < 8; i++) { S += redS[tid * 8 + i]; Q += redQ[tid * 8 + i]; }
        const float mu = S * (1.f / 768.f);
        const float var = Q * (1.f / 768.f) - mu * mu;
        muA[tid] = mu;
        rsA[tid] = rsqrtf(var + 1e-5f);
    }
    __syncthreads();

    // ---- normalize + store (f32, nontemporal: don't thrash L2)
#pragma unroll
    for (int g = 0; g < 16; ++g) {
        const int rowl = (g & 3) + 8 * (g >> 2) + 4 * half;
        const float mu = muA[rowl], rs = rsA[rowl];
        float* orow = &out[(size_t)(r0 + rowl) * DOUT + wv * 96 + lm];
#pragma unroll
        for (int ct = 0; ct < 3; ++ct) {
            __builtin_nontemporal_store((acc[ct][g] - mu) * rs * gmv[ct] + btv[ct],
                                        &orow[ct * 32]);
        }
    }
}

// ---------------------------------------------------------------- launcher
extern "C" void kernel_launch(void* const* d_in, const int* in_sizes, int n_in,
                              void* d_out, int out_size, void* d_ws, size_t ws_size,
                              hipStream_t stream)
{
    const float* x  = (const float*)d_in[0];
    const float* W  = (const float*)d_in[1];
    const float* b  = (const float*)d_in[2];
    const float* Wp = (const float*)d_in[3];
    const float* bp = (const float*)d_in[4];
    const float* Wc = (const float*)d_in[5];
    const float* bc = (const float*)d_in[6];
    const float* sc = (const float*)d_in[7];
    const float* tr = (const float*)d_in[8];
    const float* gm = (const float*)d_in[9];
    const float* bt = (const float*)d_in[10];
    float* out = (float*)d_out;
    short* ws  = (short*)d_ws;   // ~1.45 MB packed weights

    pack_kernel<<<dim3(330), dim3(256), 0, stream>>>(W, Wp, Wc, ws);
    fused_kernel<<<dim3(B_SZ / 32), dim3(512), 0, stream>>>(
        x, ws, Wp, bp, sc, tr, b, bc, gm, bt, out);
}

// Round 5
// 267.827 us; speedup vs baseline: 1.3509x; 1.1032x over previous
//
#include <hip/hip_runtime.h>
#include <math.h>

// WaveletKANClassifier, MI355X gfx950. fp32 I/O, bf16 MFMA compute.
//
// Round-8: break the per-chunk serial B-load latency chain. Evidence: in
// R0-R4 the fused chunk period is ~15.3k cycles, MFMA+VALU only ~3.8k;
// residual ~11.5k = 12 x ~1k L3 latency = the 12 B-frag loads each wave
// issues per chunk, serialized (load->wait->MFMA) because VGPR_Count 52-88
// leaves no headroom to keep operands in flight. All prior nulls (DMA,
// occupancy 2x, tile shape) kept this chain intact.
// This round:
//  - 64-row blocks (2 MFMA per B-frag: halves weight traffic) and ALL of a
//    chunk's B-frags hoisted into named registers (bfr[4][3], wi bwh/bwl[4])
//    BEFORE the MFMA cluster: 12-20 back-to-back loads, one wait, 24 MFMA.
//    ~230 VGPR, __launch_bounds__(512,2).
//  - nontemporal loads/stores REVERTED (R4: nt stores => WRITE_SIZE +33%,
//    fused +38 us).
//  - in-block haar recheck kept (2 dispatches total).

#define B_SZ  32768
#define DIN   768
#define DOUT  768
#define NWAV  48

// d_ws fragment-major layout (units: shorts). Fragment tile = 64 lanes x 8
// bf16 = 512 shorts; lane L holds M[c0+(L&31)][k0 + (L>>5)*8 + j].
#define WF_OFF   0        // W:  24 cb x 48 kb tiles = 589824
#define WPH_OFF  589824   // Wp hi: 2 ct x 48 kb = 49152
#define WPL_OFF  638976   // Wp lo: 49152
#define WCF_OFF  688128   // Wc: 24 cb x 3 kb = 36864

typedef short bf16x8 __attribute__((ext_vector_type(8)));
typedef float f32x16 __attribute__((ext_vector_type(16)));

__device__ __forceinline__ float bf2f(short u) {
    union { unsigned int i; float f; } v;
    v.i = ((unsigned int)(unsigned short)u) << 16;
    return v.f;
}
__device__ __forceinline__ short f2bf(float f) {
    union { float f; unsigned int i; } v; v.f = f;
    unsigned int r = v.i + 0x7FFFu + ((v.i >> 16) & 1u);  // RNE
    return (short)(r >> 16);
}

// ---------------------------------------------------------------- K0: pack
__global__ __launch_bounds__(256) void pack_kernel(
    const float* __restrict__ W, const float* __restrict__ Wp,
    const float* __restrict__ Wc, short* __restrict__ ws)
{
    const int gw = (blockIdx.x * 256 + threadIdx.x) >> 6;
    const int L  = threadIdx.x & 63;
    const int lm = L & 31, half = L >> 5;

    if (gw < 1152) {                       // W [768 x 768]
        const int cb = gw / 48, kb = gw % 48;
        const int row = cb * 32 + lm;
        const int k = kb * 16 + half * 8;
        bf16x8 o;
#pragma unroll
        for (int j = 0; j < 8; j++) o[j] = f2bf(W[(size_t)row * DIN + k + j]);
        *reinterpret_cast<bf16x8*>(&ws[WF_OFF + (size_t)gw * 512 + L * 8]) = o;
    } else if (gw < 1248) {                // Wp [48 x 768], hi/lo, pad rows->64
        const int t = gw - 1152;
        const int ct = t / 48, kb = t % 48;
        const int j = ct * 32 + lm;
        const int k = kb * 16 + half * 8;
        bf16x8 h, l;
#pragma unroll
        for (int jj = 0; jj < 8; jj++) {
            float v = (j < NWAV) ? Wp[(size_t)j * DIN + k + jj] : 0.f;
            const short hh = f2bf(v);
            h[jj] = hh;
            l[jj] = f2bf(v - bf2f(hh));
        }
        *reinterpret_cast<bf16x8*>(&ws[WPH_OFF + (size_t)t * 512 + L * 8]) = h;
        *reinterpret_cast<bf16x8*>(&ws[WPL_OFF + (size_t)t * 512 + L * 8]) = l;
    } else if (gw < 1320) {                // Wc [768 x 48]
        const int t = gw - 1248;
        const int cb = t / 3, kb = t % 3;
        const int row = cb * 32 + lm;
        const int k = kb * 16 + half * 8;
        bf16x8 o;
#pragma unroll
        for (int jj = 0; jj < 8; jj++) o[jj] = f2bf(Wc[(size_t)row * NWAV + k + jj]);
        *reinterpret_cast<bf16x8*>(&ws[WCF_OFF + (size_t)t * 512 + L * 8]) = o;
    }
}

// ---------------------------------------------------------------- K1: fused
// 64 rows x 768 cols per block, 8 waves x [64r x 96c], 512 blocks.
__global__ __launch_bounds__(512, 2) void fused_kernel(
    const float* __restrict__ x, const short* __restrict__ ws,
    const float* __restrict__ Wp,
    const float* __restrict__ bp, const float* __restrict__ sc,
    const float* __restrict__ tr,
    const float* __restrict__ bb, const float* __restrict__ bc,
    const float* __restrict__ gm, const float* __restrict__ bt,
    float* __restrict__ out)
{
    // x tiles: 64 rows x 64 k bf16, row stride 72 shorts (9x16B granules,
    // coprime 8 -> near-conflict-free b128 frag reads). Double-buffered.
    __shared__ __align__(16) short xh[2][64 * 72];
    __shared__ __align__(16) short xl[2][64 * 72];
    __shared__ float redS[64 * 8], redQ[64 * 8];
    __shared__ float muA[64], rsA[64];
    __shared__ unsigned flags[64];      // bit j: (row, haar j) boundary band
    __shared__ double dred[8];

    const short* WF  = ws + WF_OFF;
    const short* WPH = ws + WPH_OFF;
    const short* WPL = ws + WPL_OFF;
    const short* WCF = ws + WCF_OFF;

    const int tid = threadIdx.x;
    const int r0  = blockIdx.x * 64;
    const int L   = tid & 63;
    const int wv  = __builtin_amdgcn_readfirstlane(tid >> 6);  // wave-uniform
    const int lm  = L & 31, half = L >> 5;
    const int L8  = L * 8;
    const bool wi = (wv < 4);      // waves 0-3 also compute wi = x@Wp^T
    const int wv3 = wv * 3;
    const int wrt = wv & 1, wct = wv >> 1;     // wi tile for wv<4
    const int wct48 = wct * 48;

    if (tid < 64) flags[tid] = 0u;

    f32x16 acc[2][3];              // [rt (row 32-block)][ct (col 32-block)]
#pragma unroll
    for (int rt = 0; rt < 2; rt++)
#pragma unroll
        for (int ct = 0; ct < 3; ct++)
#pragma unroll
            for (int g = 0; g < 16; g++) acc[rt][ct][g] = 0.f;
    f32x16 wacc;                   // wi acc (waves 0-3)
#pragma unroll
    for (int g = 0; g < 16; g++) wacc[g] = 0.f;

    // staging role: thread -> (row, 8-k chunk); 8 threads per row
    const int srow = tid >> 3;
    const int sk   = (tid & 7) * 8;

    // ---- prologue: stage x chunk 0 into buf 0
    {
        const float4* xp = reinterpret_cast<const float4*>(&x[(size_t)(r0 + srow) * DIN + sk]);
        const float4 v0 = xp[0], v1 = xp[1];
        const float f[8] = {v0.x, v0.y, v0.z, v0.w, v1.x, v1.y, v1.z, v1.w};
        bf16x8 hh, ll;
#pragma unroll
        for (int i = 0; i < 8; i++) {
            const short h = f2bf(f[i]);
            hh[i] = h;
            ll[i] = f2bf(f[i] - bf2f(h));
        }
        *reinterpret_cast<bf16x8*>(&xh[0][srow * 72 + sk]) = hh;
        *reinterpret_cast<bf16x8*>(&xl[0][srow * 72 + sk]) = ll;
    }
    __syncthreads();

    // ---- K loop: 12 chunks of 64
    for (int k0i = 0; k0i < 12; ++k0i) {
        const int cur = k0i & 1;
        const int kb0 = k0i * 4;

        // x prefetch (consumed by staging at the end of this chunk)
        float4 v0, v1;
        if (k0i < 11) {
            const float4* xp = reinterpret_cast<const float4*>(
                &x[(size_t)(r0 + srow) * DIN + (k0i + 1) * 64 + sk]);
            v0 = xp[0]; v1 = xp[1];
        }

        // hoist ALL B-fragments of this chunk into registers: the 12(+8)
        // loads issue back-to-back, one wait, then the MFMA cluster.
        bf16x8 bfr[4][3];
#pragma unroll
        for (int ks = 0; ks < 4; ++ks)
#pragma unroll
            for (int ct = 0; ct < 3; ++ct)
                bfr[ks][ct] = *reinterpret_cast<const bf16x8*>(
                    &WF[((size_t)((wv3 + ct) * 48 + kb0 + ks)) * 512 + L8]);
        bf16x8 bwh[4], bwl[4];
        if (wi) {
#pragma unroll
            for (int ks = 0; ks < 4; ++ks) {
                bwh[ks] = *reinterpret_cast<const bf16x8*>(
                    &WPH[((size_t)(wct48 + kb0 + ks)) * 512 + L8]);
                bwl[ks] = *reinterpret_cast<const bf16x8*>(
                    &WPL[((size_t)(wct48 + kb0 + ks)) * 512 + L8]);
            }
        }

        // MFMA cluster: 2 rt x 3 ct x 4 ks (+3 wi per ks on waves 0-3)
#pragma unroll
        for (int ks = 0; ks < 4; ++ks) {
            const bf16x8 a0 = *reinterpret_cast<bf16x8*>(
                &xh[cur][lm * 72 + ks * 16 + half * 8]);
            const bf16x8 a1 = *reinterpret_cast<bf16x8*>(
                &xh[cur][(32 + lm) * 72 + ks * 16 + half * 8]);
#pragma unroll
            for (int ct = 0; ct < 3; ++ct) {
                acc[0][ct] = __builtin_amdgcn_mfma_f32_32x32x16_bf16(a0, bfr[ks][ct], acc[0][ct], 0, 0, 0);
                acc[1][ct] = __builtin_amdgcn_mfma_f32_32x32x16_bf16(a1, bfr[ks][ct], acc[1][ct], 0, 0, 0);
            }
            if (wi) {
                const bf16x8 ah = wrt ? a1 : a0;
                const bf16x8 al = *reinterpret_cast<bf16x8*>(
                    &xl[cur][(wrt * 32 + lm) * 72 + ks * 16 + half * 8]);
                wacc = __builtin_amdgcn_mfma_f32_32x32x16_bf16(ah, bwl[ks], wacc, 0, 0, 0);
                wacc = __builtin_amdgcn_mfma_f32_32x32x16_bf16(al, bwh[ks], wacc, 0, 0, 0);
                wacc = __builtin_amdgcn_mfma_f32_32x32x16_bf16(ah, bwh[ks], wacc, 0, 0, 0);
            }
        }

        // stage next x chunk into 1-cur
        if (k0i < 11) {
            const float f[8] = {v0.x, v0.y, v0.z, v0.w, v1.x, v1.y, v1.z, v1.w};
            bf16x8 hh, ll;
#pragma unroll
            for (int i = 0; i < 8; i++) {
                const short h = f2bf(f[i]);
                hh[i] = h;
                ll[i] = f2bf(f[i] - bf2f(h));
            }
            *reinterpret_cast<bf16x8*>(&xh[1 - cur][srow * 72 + sk]) = hh;
            *reinterpret_cast<bf16x8*>(&xl[1 - cur][srow * 72 + sk]) = ll;
        }
        __syncthreads();
    }

    // ---- wavelet activation + GELU -> wav tile in LDS (reuse xh[0])
    short* wavL = &xh[0][0];
    if (wi) {
        const int j = wct * 32 + lm;
        if (j < NWAV) {
            const float bpv = bp[j], scv = sc[j], trv = tr[j];
#pragma unroll
            for (int g = 0; g < 16; ++g) {
                const int rowl = wrt * 32 + (g & 3) + 8 * (g >> 2) + 4 * half;  // C/D map
                const float wiv = wacc[g] + bpv;
                const float s = (wiv - trv) / scv;
                float w;
                if (j < 16) {
                    // haar: flag boundary band for the in-block fp64 recheck
                    const float dmin = fminf(fabsf(s), fminf(fabsf(s - 0.5f), fabsf(s - 1.0f)));
                    if (dmin < 2e-4f) atomicOr(&flags[rowl], 1u << j);
                    w = (s >= 0.f && s < 0.5f) ? 1.f : ((s >= 0.5f && s < 1.f) ? -1.f : 0.f);
                } else if (j < 32) {
                    w = (1.f - s * s) * expf(-0.5f * s * s);
                } else {
                    w = cosf(5.f * s) * expf(-0.5f * s * s);
                }
                const float gel = 0.5f * w * (1.f + erff(w * 0.70710678118654752f));
                wavL[rowl * 72 + j] = f2bf(gel);
            }
        }
    }
    __syncthreads();

    // ---- block-parallel fp64 recheck of flagged (row, j) haar entries.
    // Rare; uniform control flow: all 512 threads walk the same LDS flag
    // words; each recheck is a cooperative 768-term fp64 dot, patching
    // wavL before the Wc MFMA.
#pragma unroll 1
    for (int fr = 0; fr < 64; ++fr) {
        unsigned m = flags[fr];
        while (m) {
            const int j = __ffs(m) - 1;
            m &= m - 1;
            const float* xr = &x[(size_t)(r0 + fr) * DIN];
            const float* wr = &Wp[(size_t)j * DIN];
            double a = (double)xr[tid] * (double)wr[tid];
            if (tid < DIN - 512)
                a += (double)xr[tid + 512] * (double)wr[tid + 512];
            a += __shfl_xor(a, 1);  a += __shfl_xor(a, 2);
            a += __shfl_xor(a, 4);  a += __shfl_xor(a, 8);
            a += __shfl_xor(a, 16); a += __shfl_xor(a, 32);
            if (L == 0) dred[wv] = a;
            __syncthreads();
            if (tid == 0) {
                double wid = (double)bp[j];
#pragma unroll
                for (int i = 0; i < 8; i++) wid += dred[i];
                const double sd = (wid - (double)tr[j]) / (double)sc[j];
                const double w = (sd >= 0.0 && sd < 0.5) ? 1.0
                               : ((sd >= 0.5 && sd < 1.0) ? -1.0 : 0.0);
                const double gel = 0.5 * w * (1.0 + erf(w * 0.70710678118654752));
                wavL[fr * 72 + j] = f2bf((float)gel);
            }
            __syncthreads();
        }
    }

    // ---- h += wav @ Wc^T  (K=48 -> 3 ksteps)
#pragma unroll
    for (int ks = 0; ks < 3; ++ks) {
        const bf16x8 a0 = *reinterpret_cast<bf16x8*>(&wavL[lm * 72 + ks * 16 + half * 8]);
        const bf16x8 a1 = *reinterpret_cast<bf16x8*>(&wavL[(32 + lm) * 72 + ks * 16 + half * 8]);
#pragma unroll
        for (int ct = 0; ct < 3; ++ct) {
            const bf16x8 b = *reinterpret_cast<const bf16x8*>(
                &WCF[((size_t)((wv3 + ct) * 3 + ks)) * 512 + L8]);
            acc[0][ct] = __builtin_amdgcn_mfma_f32_32x32x16_bf16(a0, b, acc[0][ct], 0, 0, 0);
            acc[1][ct] = __builtin_amdgcn_mfma_f32_32x32x16_bf16(a1, b, acc[1][ct], 0, 0, 0);
        }
    }

    // ---- bias + LN reduction
    float bias[3], gmv[3], btv[3];
#pragma unroll
    for (int ct = 0; ct < 3; ++ct) {
        const int col = wv * 96 + ct * 32 + lm;
        bias[ct] = bb[col] + bc[col];
        gmv[ct] = gm[col];
        btv[ct] = bt[col];
    }
#pragma unroll
    for (int rt = 0; rt < 2; ++rt) {
#pragma unroll
        for (int g = 0; g < 16; ++g) {
            const float v0 = acc[rt][0][g] + bias[0];
            const float v1 = acc[rt][1][g] + bias[1];
            const float v2 = acc[rt][2][g] + bias[2];
            acc[rt][0][g] = v0; acc[rt][1][g] = v1; acc[rt][2][g] = v2;
            float s1 = v0 + v1 + v2;
            float s2 = v0 * v0 + v1 * v1 + v2 * v2;
            // reduce across the 32 lanes of this half (same output row)
            s1 += __shfl_xor(s1, 1);  s2 += __shfl_xor(s2, 1);
            s1 += __shfl_xor(s1, 2);  s2 += __shfl_xor(s2, 2);
            s1 += __shfl_xor(s1, 4);  s2 += __shfl_xor(s2, 4);
            s1 += __shfl_xor(s1, 8);  s2 += __shfl_xor(s2, 8);
            s1 += __shfl_xor(s1, 16); s2 += __shfl_xor(s2, 16);
            if (lm == 0) {
                const int rowl = rt * 32 + (g & 3) + 8 * (g >> 2) + 4 * half;
                redS[rowl * 8 + wv] = s1;
                redQ[rowl * 8 + wv] = s2;
            }
        }
    }
    __syncthreads();
    if (tid < 64) {
        float S = 0.f, Q = 0.f;
#pragma unroll
        for (int i = 0; i < 8; i++) { S += redS[tid * 8 + i]; Q += redQ[tid * 8 + i]; }
        const float mu = S * (1.f / 768.f);
        const float var = Q * (1.f / 768.f) - mu * mu;
        muA[tid] = mu;
        rsA[tid] = rsqrtf(var + 1e-5f);
    }
    __syncthreads();

    // ---- normalize + store (f32)
#pragma unroll
    for (int rt = 0; rt < 2; ++rt) {
#pragma unroll
        for (int g = 0; g < 16; ++g) {
            const int rowl = rt * 32 + (g & 3) + 8 * (g >> 2) + 4 * half;
            const float mu = muA[rowl], rs = rsA[rowl];
            float* orow = &out[(size_t)(r0 + rowl) * DOUT + wv * 96 + lm];
#pragma unroll
            for (int ct = 0; ct < 3; ++ct) {
                orow[ct * 32] = (acc[rt][ct][g] - mu) * rs * gmv[ct] + btv[ct];
            }
        }
    }
}

// ---------------------------------------------------------------- launcher
extern "C" void kernel_launch(void* const* d_in, const int* in_sizes, int n_in,
                              void* d_out, int out_size, void* d_ws, size_t ws_size,
                              hipStream_t stream)
{
    const float* x  = (const float*)d_in[0];
    const float* W  = (const float*)d_in[1];
    const float* b  = (const float*)d_in[2];
    const float* Wp = (const float*)d_in[3];
    const float* bp = (const float*)d_in[4];
    const float* Wc = (const float*)d_in[5];
    const float* bc = (const float*)d_in[6];
    const float* sc = (const float*)d_in[7];
    const float* tr = (const float*)d_in[8];
    const float* gm = (const float*)d_in[9];
    const float* bt = (const float*)d_in[10];
    float* out = (float*)d_out;
    short* ws  = (short*)d_ws;   // ~1.45 MB packed weights

    pack_kernel<<<dim3(330), dim3(256), 0, stream>>>(W, Wp, Wc, ws);
    fused_kernel<<<dim3(B_SZ / 64), dim3(512), 0, stream>>>(
        x, ws, Wp, bp, sc, tr, b, bc, gm, bt, out);
}

// Round 6
// 264.921 us; speedup vs baseline: 1.3657x; 1.0110x over previous
//
#include <hip/hip_runtime.h>
#include <math.h>

// WaveletKANClassifier, MI355X gfx950. fp32 I/O, bf16 MFMA compute.
//
// Round-9: force the B-fragment batch issue. R8's source-level hoist only
// partially landed: VGPR_Count 116 (too low to hold bfr[4][3]+wi frags)
// => the scheduler re-sank loads to their uses, keeping most of the
// ~12 x ~700cyc serial chain (134 us, still ~66% stall per chunk).
// This round: __builtin_amdgcn_sched_barrier(0) between the load group
// and the MFMA cluster (guide rule 18: the only fence hipcc respects).
// Chunk order: [12(+8) B-frag loads][2 x-prefetch loads][sched_barrier(0)]
// [MFMA cluster: vmcnt(2), x stays in flight][staging][barrier].
// Expected VGPR ~200 (the observable that the hoist stuck).

#define B_SZ  32768
#define DIN   768
#define DOUT  768
#define NWAV  48

// d_ws fragment-major layout (units: shorts). Fragment tile = 64 lanes x 8
// bf16 = 512 shorts; lane L holds M[c0+(L&31)][k0 + (L>>5)*8 + j].
#define WF_OFF   0        // W:  24 cb x 48 kb tiles = 589824
#define WPH_OFF  589824   // Wp hi: 2 ct x 48 kb = 49152
#define WPL_OFF  638976   // Wp lo: 49152
#define WCF_OFF  688128   // Wc: 24 cb x 3 kb = 36864

typedef short bf16x8 __attribute__((ext_vector_type(8)));
typedef float f32x16 __attribute__((ext_vector_type(16)));

__device__ __forceinline__ float bf2f(short u) {
    union { unsigned int i; float f; } v;
    v.i = ((unsigned int)(unsigned short)u) << 16;
    return v.f;
}
__device__ __forceinline__ short f2bf(float f) {
    union { float f; unsigned int i; } v; v.f = f;
    unsigned int r = v.i + 0x7FFFu + ((v.i >> 16) & 1u);  // RNE
    return (short)(r >> 16);
}

// ---------------------------------------------------------------- K0: pack
__global__ __launch_bounds__(256) void pack_kernel(
    const float* __restrict__ W, const float* __restrict__ Wp,
    const float* __restrict__ Wc, short* __restrict__ ws)
{
    const int gw = (blockIdx.x * 256 + threadIdx.x) >> 6;
    const int L  = threadIdx.x & 63;
    const int lm = L & 31, half = L >> 5;

    if (gw < 1152) {                       // W [768 x 768]
        const int cb = gw / 48, kb = gw % 48;
        const int row = cb * 32 + lm;
        const int k = kb * 16 + half * 8;
        bf16x8 o;
#pragma unroll
        for (int j = 0; j < 8; j++) o[j] = f2bf(W[(size_t)row * DIN + k + j]);
        *reinterpret_cast<bf16x8*>(&ws[WF_OFF + (size_t)gw * 512 + L * 8]) = o;
    } else if (gw < 1248) {                // Wp [48 x 768], hi/lo, pad rows->64
        const int t = gw - 1152;
        const int ct = t / 48, kb = t % 48;
        const int j = ct * 32 + lm;
        const int k = kb * 16 + half * 8;
        bf16x8 h, l;
#pragma unroll
        for (int jj = 0; jj < 8; jj++) {
            float v = (j < NWAV) ? Wp[(size_t)j * DIN + k + jj] : 0.f;
            const short hh = f2bf(v);
            h[jj] = hh;
            l[jj] = f2bf(v - bf2f(hh));
        }
        *reinterpret_cast<bf16x8*>(&ws[WPH_OFF + (size_t)t * 512 + L * 8]) = h;
        *reinterpret_cast<bf16x8*>(&ws[WPL_OFF + (size_t)t * 512 + L * 8]) = l;
    } else if (gw < 1320) {                // Wc [768 x 48]
        const int t = gw - 1248;
        const int cb = t / 3, kb = t % 3;
        const int row = cb * 32 + lm;
        const int k = kb * 16 + half * 8;
        bf16x8 o;
#pragma unroll
        for (int jj = 0; jj < 8; jj++) o[jj] = f2bf(Wc[(size_t)row * NWAV + k + jj]);
        *reinterpret_cast<bf16x8*>(&ws[WCF_OFF + (size_t)t * 512 + L * 8]) = o;
    }
}

// ---------------------------------------------------------------- K1: fused
// 64 rows x 768 cols per block, 8 waves x [64r x 96c], 512 blocks.
__global__ __launch_bounds__(512, 2) void fused_kernel(
    const float* __restrict__ x, const short* __restrict__ ws,
    const float* __restrict__ Wp,
    const float* __restrict__ bp, const float* __restrict__ sc,
    const float* __restrict__ tr,
    const float* __restrict__ bb, const float* __restrict__ bc,
    const float* __restrict__ gm, const float* __restrict__ bt,
    float* __restrict__ out)
{
    // x tiles: 64 rows x 64 k bf16, row stride 72 shorts (9x16B granules,
    // coprime 8 -> near-conflict-free b128 frag reads). Double-buffered.
    __shared__ __align__(16) short xh[2][64 * 72];
    __shared__ __align__(16) short xl[2][64 * 72];
    __shared__ float redS[64 * 8], redQ[64 * 8];
    __shared__ float muA[64], rsA[64];
    __shared__ unsigned flags[64];      // bit j: (row, haar j) boundary band
    __shared__ double dred[8];

    const short* WF  = ws + WF_OFF;
    const short* WPH = ws + WPH_OFF;
    const short* WPL = ws + WPL_OFF;
    const short* WCF = ws + WCF_OFF;

    const int tid = threadIdx.x;
    const int r0  = blockIdx.x * 64;
    const int L   = tid & 63;
    const int wv  = __builtin_amdgcn_readfirstlane(tid >> 6);  // wave-uniform
    const int lm  = L & 31, half = L >> 5;
    const int L8  = L * 8;
    const bool wi = (wv < 4);      // waves 0-3 also compute wi = x@Wp^T
    const int wv3 = wv * 3;
    const int wrt = wv & 1, wct = wv >> 1;     // wi tile for wv<4
    const int wct48 = wct * 48;

    if (tid < 64) flags[tid] = 0u;

    f32x16 acc[2][3];              // [rt (row 32-block)][ct (col 32-block)]
#pragma unroll
    for (int rt = 0; rt < 2; rt++)
#pragma unroll
        for (int ct = 0; ct < 3; ct++)
#pragma unroll
            for (int g = 0; g < 16; g++) acc[rt][ct][g] = 0.f;
    f32x16 wacc;                   // wi acc (waves 0-3)
#pragma unroll
    for (int g = 0; g < 16; g++) wacc[g] = 0.f;

    // staging role: thread -> (row, 8-k chunk); 8 threads per row
    const int srow = tid >> 3;
    const int sk   = (tid & 7) * 8;

    // ---- prologue: stage x chunk 0 into buf 0
    {
        const float4* xp = reinterpret_cast<const float4*>(&x[(size_t)(r0 + srow) * DIN + sk]);
        const float4 v0 = xp[0], v1 = xp[1];
        const float f[8] = {v0.x, v0.y, v0.z, v0.w, v1.x, v1.y, v1.z, v1.w};
        bf16x8 hh, ll;
#pragma unroll
        for (int i = 0; i < 8; i++) {
            const short h = f2bf(f[i]);
            hh[i] = h;
            ll[i] = f2bf(f[i] - bf2f(h));
        }
        *reinterpret_cast<bf16x8*>(&xh[0][srow * 72 + sk]) = hh;
        *reinterpret_cast<bf16x8*>(&xl[0][srow * 72 + sk]) = ll;
    }
    __syncthreads();

    // ---- K loop: 12 chunks of 64
    for (int k0i = 0; k0i < 12; ++k0i) {
        const int cur = k0i & 1;
        const int kb0 = k0i * 4;

        // (1) issue ALL B-fragment loads of this chunk, back-to-back
        bf16x8 bfr[4][3];
#pragma unroll
        for (int ks = 0; ks < 4; ++ks)
#pragma unroll
            for (int ct = 0; ct < 3; ++ct)
                bfr[ks][ct] = *reinterpret_cast<const bf16x8*>(
                    &WF[((size_t)((wv3 + ct) * 48 + kb0 + ks)) * 512 + L8]);
        bf16x8 bwh[4], bwl[4];
        if (wi) {
#pragma unroll
            for (int ks = 0; ks < 4; ++ks) {
                bwh[ks] = *reinterpret_cast<const bf16x8*>(
                    &WPH[((size_t)(wct48 + kb0 + ks)) * 512 + L8]);
                bwl[ks] = *reinterpret_cast<const bf16x8*>(
                    &WPL[((size_t)(wct48 + kb0 + ks)) * 512 + L8]);
            }
        }

        // (2) issue x prefetch (consumed after the MFMA cluster)
        float4 v0, v1;
        if (k0i < 11) {
            const float4* xp = reinterpret_cast<const float4*>(
                &x[(size_t)(r0 + srow) * DIN + (k0i + 1) * 64 + sk]);
            v0 = xp[0]; v1 = xp[1];
        }

        // (3) fence: nothing above may sink below (loads stay batched)
        __builtin_amdgcn_sched_barrier(0);

        // (4) MFMA cluster: 2 rt x 3 ct x 4 ks (+3 wi per ks on waves 0-3)
#pragma unroll
        for (int ks = 0; ks < 4; ++ks) {
            const bf16x8 a0 = *reinterpret_cast<bf16x8*>(
                &xh[cur][lm * 72 + ks * 16 + half * 8]);
            const bf16x8 a1 = *reinterpret_cast<bf16x8*>(
                &xh[cur][(32 + lm) * 72 + ks * 16 + half * 8]);
#pragma unroll
            for (int ct = 0; ct < 3; ++ct) {
                acc[0][ct] = __builtin_amdgcn_mfma_f32_32x32x16_bf16(a0, bfr[ks][ct], acc[0][ct], 0, 0, 0);
                acc[1][ct] = __builtin_amdgcn_mfma_f32_32x32x16_bf16(a1, bfr[ks][ct], acc[1][ct], 0, 0, 0);
            }
            if (wi) {
                const bf16x8 ah = wrt ? a1 : a0;
                const bf16x8 al = *reinterpret_cast<bf16x8*>(
                    &xl[cur][(wrt * 32 + lm) * 72 + ks * 16 + half * 8]);
                wacc = __builtin_amdgcn_mfma_f32_32x32x16_bf16(ah, bwl[ks], wacc, 0, 0, 0);
                wacc = __builtin_amdgcn_mfma_f32_32x32x16_bf16(al, bwh[ks], wacc, 0, 0, 0);
                wacc = __builtin_amdgcn_mfma_f32_32x32x16_bf16(ah, bwh[ks], wacc, 0, 0, 0);
            }
        }

        // (5) stage next x chunk into 1-cur
        if (k0i < 11) {
            const float f[8] = {v0.x, v0.y, v0.z, v0.w, v1.x, v1.y, v1.z, v1.w};
            bf16x8 hh, ll;
#pragma unroll
            for (int i = 0; i < 8; i++) {
                const short h = f2bf(f[i]);
                hh[i] = h;
                ll[i] = f2bf(f[i] - bf2f(h));
            }
            *reinterpret_cast<bf16x8*>(&xh[1 - cur][srow * 72 + sk]) = hh;
            *reinterpret_cast<bf16x8*>(&xl[1 - cur][srow * 72 + sk]) = ll;
        }
        __syncthreads();
    }

    // ---- wavelet activation + GELU -> wav tile in LDS (reuse xh[0])
    short* wavL = &xh[0][0];
    if (wi) {
        const int j = wct * 32 + lm;
        if (j < NWAV) {
            const float bpv = bp[j], scv = sc[j], trv = tr[j];
#pragma unroll
            for (int g = 0; g < 16; ++g) {
                const int rowl = wrt * 32 + (g & 3) + 8 * (g >> 2) + 4 * half;  // C/D map
                const float wiv = wacc[g] + bpv;
                const float s = (wiv - trv) / scv;
                float w;
                if (j < 16) {
                    // haar: flag boundary band for the in-block fp64 recheck
                    const float dmin = fminf(fabsf(s), fminf(fabsf(s - 0.5f), fabsf(s - 1.0f)));
                    if (dmin < 2e-4f) atomicOr(&flags[rowl], 1u << j);
                    w = (s >= 0.f && s < 0.5f) ? 1.f : ((s >= 0.5f && s < 1.f) ? -1.f : 0.f);
                } else if (j < 32) {
                    w = (1.f - s * s) * expf(-0.5f * s * s);
                } else {
                    w = cosf(5.f * s) * expf(-0.5f * s * s);
                }
                const float gel = 0.5f * w * (1.f + erff(w * 0.70710678118654752f));
                wavL[rowl * 72 + j] = f2bf(gel);
            }
        }
    }
    __syncthreads();

    // ---- block-parallel fp64 recheck of flagged (row, j) haar entries.
    // Rare; uniform control flow: all 512 threads walk the same LDS flag
    // words; each recheck is a cooperative 768-term fp64 dot, patching
    // wavL before the Wc MFMA.
#pragma unroll 1
    for (int fr = 0; fr < 64; ++fr) {
        unsigned m = flags[fr];
        while (m) {
            const int j = __ffs(m) - 1;
            m &= m - 1;
            const float* xr = &x[(size_t)(r0 + fr) * DIN];
            const float* wr = &Wp[(size_t)j * DIN];
            double a = (double)xr[tid] * (double)wr[tid];
            if (tid < DIN - 512)
                a += (double)xr[tid + 512] * (double)wr[tid + 512];
            a += __shfl_xor(a, 1);  a += __shfl_xor(a, 2);
            a += __shfl_xor(a, 4);  a += __shfl_xor(a, 8);
            a += __shfl_xor(a, 16); a += __shfl_xor(a, 32);
            if (L == 0) dred[wv] = a;
            __syncthreads();
            if (tid == 0) {
                double wid = (double)bp[j];
#pragma unroll
                for (int i = 0; i < 8; i++) wid += dred[i];
                const double sd = (wid - (double)tr[j]) / (double)sc[j];
                const double w = (sd >= 0.0 && sd < 0.5) ? 1.0
                               : ((sd >= 0.5 && sd < 1.0) ? -1.0 : 0.0);
                const double gel = 0.5 * w * (1.0 + erf(w * 0.70710678118654752));
                wavL[fr * 72 + j] = f2bf((float)gel);
            }
            __syncthreads();
        }
    }

    // ---- h += wav @ Wc^T  (K=48 -> 3 ksteps)
#pragma unroll
    for (int ks = 0; ks < 3; ++ks) {
        const bf16x8 a0 = *reinterpret_cast<bf16x8*>(&wavL[lm * 72 + ks * 16 + half * 8]);
        const bf16x8 a1 = *reinterpret_cast<bf16x8*>(&wavL[(32 + lm) * 72 + ks * 16 + half * 8]);
#pragma unroll
        for (int ct = 0; ct < 3; ++ct) {
            const bf16x8 b = *reinterpret_cast<const bf16x8*>(
                &WCF[((size_t)((wv3 + ct) * 3 + ks)) * 512 + L8]);
            acc[0][ct] = __builtin_amdgcn_mfma_f32_32x32x16_bf16(a0, b, acc[0][ct], 0, 0, 0);
            acc[1][ct] = __builtin_amdgcn_mfma_f32_32x32x16_bf16(a1, b, acc[1][ct], 0, 0, 0);
        }
    }

    // ---- bias + LN reduction
    float bias[3], gmv[3], btv[3];
#pragma unroll
    for (int ct = 0; ct < 3; ++ct) {
        const int col = wv * 96 + ct * 32 + lm;
        bias[ct] = bb[col] + bc[col];
        gmv[ct] = gm[col];
        btv[ct] = bt[col];
    }
#pragma unroll
    for (int rt = 0; rt < 2; ++rt) {
#pragma unroll
        for (int g = 0; g < 16; ++g) {
            const float v0 = acc[rt][0][g] + bias[0];
            const float v1 = acc[rt][1][g] + bias[1];
            const float v2 = acc[rt][2][g] + bias[2];
            acc[rt][0][g] = v0; acc[rt][1][g] = v1; acc[rt][2][g] = v2;
            float s1 = v0 + v1 + v2;
            float s2 = v0 * v0 + v1 * v1 + v2 * v2;
            // reduce across the 32 lanes of this half (same output row)
            s1 += __shfl_xor(s1, 1);  s2 += __shfl_xor(s2, 1);
            s1 += __shfl_xor(s1, 2);  s2 += __shfl_xor(s2, 2);
            s1 += __shfl_xor(s1, 4);  s2 += __shfl_xor(s2, 4);
            s1 += __shfl_xor(s1, 8);  s2 += __shfl_xor(s2, 8);
            s1 += __shfl_xor(s1, 16); s2 += __shfl_xor(s2, 16);
            if (lm == 0) {
                const int rowl = rt * 32 + (g & 3) + 8 * (g >> 2) + 4 * half;
                redS[rowl * 8 + wv] = s1;
                redQ[rowl * 8 + wv] = s2;
            }
        }
    }
    __syncthreads();
    if (tid < 64) {
        float S = 0.f, Q = 0.f;
#pragma unroll
        for (int i = 0; i < 8; i++) { S += redS[tid * 8 + i]; Q += redQ[tid * 8 + i]; }
        const float mu = S * (1.f / 768.f);
        const float var = Q * (1.f / 768.f) - mu * mu;
        muA[tid] = mu;
        rsA[tid] = rsqrtf(var + 1e-5f);
    }
    __syncthreads();

    // ---- normalize + store (f32)
#pragma unroll
    for (int rt = 0; rt < 2; ++rt) {
#pragma unroll
        for (int g = 0; g < 16; ++g) {
            const int rowl = rt * 32 + (g & 3) + 8 * (g >> 2) + 4 * half;
            const float mu = muA[rowl], rs = rsA[rowl];
            float* orow = &out[(size_t)(r0 + rowl) * DOUT + wv * 96 + lm];
#pragma unroll
            for (int ct = 0; ct < 3; ++ct) {
                orow[ct * 32] = (acc[rt][ct][g] - mu) * rs * gmv[ct] + btv[ct];
            }
        }
    }
}

// ---------------------------------------------------------------- launcher
extern "C" void kernel_launch(void* const* d_in, const int* in_sizes, int n_in,
                              void* d_out, int out_size, void* d_ws, size_t ws_size,
                              hipStream_t stream)
{
    const float* x  = (const float*)d_in[0];
    const float* W  = (const float*)d_in[1];
    const float* b  = (const float*)d_in[2];
    const float* Wp = (const float*)d_in[3];
    const float* bp = (const float*)d_in[4];
    const float* Wc = (const float*)d_in[5];
    const float* bc = (const float*)d_in[6];
    const float* sc = (const float*)d_in[7];
    const float* tr = (const float*)d_in[8];
    const float* gm = (const float*)d_in[9];
    const float* bt = (const float*)d_in[10];
    float* out = (float*)d_out;
    short* ws  = (short*)d_ws;   // ~1.45 MB packed weights

    pack_kernel<<<dim3(330), dim3(256), 0, stream>>>(W, Wp, Wc, ws);
    fused_kernel<<<dim3(B_SZ / 64), dim3(512), 0, stream>>>(
        x, ws, Wp, bp, sc, tr, b, bc, gm, bt, out);
}